// Round 24
// baseline (78.269 us; speedup 1.0000x reference)
//
#include <hip/hip_runtime.h>

typedef unsigned short u16;
typedef float f32x4 __attribute__((ext_vector_type(4)));
typedef unsigned int u32x4 __attribute__((ext_vector_type(4)));
typedef unsigned short u16x4 __attribute__((ext_vector_type(4)));
typedef unsigned short u16x8 __attribute__((ext_vector_type(8)));
typedef __bf16 bf16x8 __attribute__((ext_vector_type(8)));

#define DEVFN static __device__ __forceinline__

DEVFN float bf2f(u16 u) {
    unsigned int i = ((unsigned int)u) << 16;
    float f;
    __builtin_memcpy(&f, &i, 4);
    return f;
}
// native RNE bf16 convert — bit-identical to the +0x7fff RNE hack [r18]
DEVFN u16 f2bf(float f) {
    __bf16 h = (__bf16)f;
    return __builtin_bit_cast(u16, h);
}

DEVFN bf16x8 ldb(const u16* p) { return __builtin_bit_cast(bf16x8, *(const u16x8*)p); }

// stage 8 fp32 -> 8 bf16 (RNE, native casts)
DEVFN void stage8(u16* dst, const float* src) {
    float4 a = *(const float4*)src;
    float4 b = *(const float4*)(src + 4);
    u16x8 m;
    m[0] = f2bf(a.x); m[1] = f2bf(a.y); m[2] = f2bf(a.z); m[3] = f2bf(a.w);
    m[4] = f2bf(b.x); m[5] = f2bf(b.y); m[6] = f2bf(b.z); m[7] = f2bf(b.w);
    *(u16x8*)dst = m;
}

// 16x16x32: C/D: col=lane&15 (Brow), row=(lane>>4)*4+reg (Arow)  (HW-verified r2)
DEVFN f32x4 mfma16(bf16x8 a, bf16x8 b, f32x4 c) {
    return __builtin_amdgcn_mfma_f32_16x16x32_bf16(a, b, c, 0, 0, 0);
}

// raw v_exp_f32 (skips denormal fixup). Args are |x|<~4 or -1e30 (raw op -> 0). [r10: WIN]
#if __has_builtin(__builtin_amdgcn_exp2f)
DEVFN float ex2(float x) { return __builtin_amdgcn_exp2f(x); }
#else
DEVFN float ex2(float x) { return exp2f(x); }
#endif

// LN stats for a float4 over a 32-lane row group: 5-level butterfly (offsets <32 keep bit5)
DEVFN void ln_stats(float4 v, float& mean, float& rs) {
    float s = (v.x + v.y) + (v.z + v.w);
    float q = v.x * v.x + v.y * v.y + v.z * v.z + v.w * v.w;
#pragma unroll
    for (int off = 1; off < 32; off <<= 1) {
        s += __shfl_xor(s, off);
        q += __shfl_xor(q, off);
    }
    mean = s * (1.0f / 128.0f);
    float var = q * (1.0f / 128.0f) - mean * mean;
    rs = rsqrtf(var + 1e-5f);
}
DEVFN u16x4 ln_pack(float4 v, float mean, float rs) {
    u16x4 o;
    o[0] = f2bf((v.x - mean) * rs);
    o[1] = f2bf((v.y - mean) * rs);
    o[2] = f2bf((v.z - mean) * rs);
    o[3] = f2bf((v.w - mean) * rs);
    return o;
}

// ---------------- fused 4-layer conv stack + final LN + QKV projection (r18/r19 proven) ----------------
__global__ __launch_bounds__(512) void k_convstack(const float* __restrict__ x,
                                                   const float* __restrict__ ptw,
                                                   const float* __restrict__ dwAll,
                                                   const float* __restrict__ dbAll,
                                                   const float* __restrict__ pbAll,
                                                   const float* __restrict__ wq,
                                                   const float* __restrict__ wk,
                                                   const float* __restrict__ wv,
                                                   const int* __restrict__ mask,
                                                   float* __restrict__ dst,
                                                   u16* __restrict__ qb,
                                                   u16* __restrict__ kb,
                                                   u16* __restrict__ vb) {
    __shared__ alignas(16) float sCur[56 * 128];  // fp32 residual stream
    __shared__ alignas(16) u16 sLC[64 * 128];     // LN rows / conv tile / final LN A-tile
    __shared__ alignas(16) u16 sW[128 * 128];     // weight tile (bf16, swizzled), restaged
    __shared__ int sred[8];
    int tid = threadIdx.x;
    int w = tid >> 6, l64 = tid & 63;
    int sub = l64 >> 5, l32 = l64 & 31;           // row-half and lane-in-row for LN
    int b = blockIdx.x >> 5, lt = blockIdx.x & 31;
    int l0 = lt << 5;
    const float* xb = x + ((size_t)(b << 10)) * 128;
    float* dstb = dst + ((size_t)(b << 10)) * 128;
    int row16 = l64 & 15, g = l64 >> 4;
    f32x4 zf = {0.f, 0.f, 0.f, 0.f};

    // inline per-batch mask sum (for Q prescale)
    {
        int2 mm = *(const int2*)&mask[(b << 10) + (tid << 1)];
        int part = mm.x + mm.y;
#pragma unroll
        for (int off = 1; off < 64; off <<= 1) part += __shfl_xor(part, off);
        if (l64 == 0) sred[w] = part;
    }

    for (int j = 0; j < 4; j++) {
        int lo = 3 * j;
        int hi = 56 - 3 * j;
        int cstart = lo + 3;
        int width = 50 - 6 * j;

        // --- LN phase: 2 rows per wave-pass ---
        for (int r = lo + (w << 1) + sub; r < hi; r += 16) {
            int al = l0 - 12 + r;
            bool ok = (al >= 0) && (al < 1024);
            float4 v = {0.f, 0.f, 0.f, 0.f};
            if (ok) {
                if (j == 0) v = *(const float4*)&xb[(size_t)al * 128 + (l32 << 2)];
                else        v = *(const float4*)&sCur[r * 128 + (l32 << 2)];
            }
            if (j == 0) *(float4*)&sCur[r * 128 + (l32 << 2)] = v;
            float mean, rs;
            ln_stats(v, mean, rs);
            u16x4 pk = {0, 0, 0, 0};
            if (ok) pk = ln_pack(v, mean, rs);
            *(u16x4*)&sLC[r * 128 + (l32 << 2)] = pk;
        }
        __syncthreads();

        // --- stage W_j (fp32 -> bf16 inline) ---
        const float* Wp = ptw + j * 16384;
#pragma unroll
        for (int i = 0; i < 4; i++) {
            int e = i * 512 + tid;
            int r = e >> 4, cc = e & 15;
            stage8(&sW[r * 128 + ((cc ^ (r & 15)) << 3)], &Wp[(r << 7) + (cc << 3)]);
        }

        // --- depthwise conv to regs ---
        int cp = l64;
        const float* dwp = dwAll + j * 896;
        float w0[7], w1[7];
#pragma unroll
        for (int k = 0; k < 7; k++) {
            w0[k] = dwp[(cp * 2) * 7 + k];
            w1[k] = dwp[(cp * 2 + 1) * 7 + k];
        }
        float b0 = dbAll[j * 128 + cp * 2], b1 = dbAll[j * 128 + cp * 2 + 1];
        int base = cstart + w * 7;
        float v0[13], v1[13];
#pragma unroll
        for (int k = 0; k < 13; k++) {
            int rw = base - 3 + k;
            rw = rw < 63 ? rw : 63;
            unsigned int pk = *(const unsigned int*)&sLC[rw * 128 + (cp << 1)];
            v0[k] = bf2f((u16)(pk & 0xffffu));
            v1[k] = bf2f((u16)(pk >> 16));
        }
        float a0[7], a1[7];
#pragma unroll
        for (int rr = 0; rr < 7; rr++) {
            float s0 = b0, s1 = b1;
#pragma unroll
            for (int k = 0; k < 7; k++) {
                s0 += v0[rr + k] * w0[k];
                s1 += v1[rr + k] * w1[k];
            }
            a0[rr] = s0;
            a1[rr] = s1;
        }
        __syncthreads();

#pragma unroll
        for (int rr = 0; rr < 7; rr++) {
            int rel = w * 7 + rr;
            float s0 = (rel < width) ? a0[rr] : 0.0f;
            float s1 = (rel < width) ? a1[rr] : 0.0f;
            int cc = cp >> 2;
            *(unsigned int*)&sLC[rel * 128 + ((cc ^ (rel & 15)) << 3) + ((cp & 3) << 1)] =
                (unsigned int)f2bf(s0) | ((unsigned int)f2bf(s1) << 16);
        }
        *(unsigned int*)&sLC[(56 + w) * 128 + (l64 << 1)] = 0;
        __syncthreads();

        // --- pointwise GEMM ---
        int mh = w >> 1, nh = w & 1;
        f32x4 acc[4] = {zf, zf, zf, zf};
#pragma unroll
        for (int kk = 0; kk < 4; kk++) {
            int chunk = ((kk * 4 + g) ^ row16) << 3;
            bf16x8 a = ldb(&sLC[(mh * 16 + row16) * 128 + chunk]);
#pragma unroll
            for (int n = 0; n < 4; n++) {
                bf16x8 bfr = ldb(&sW[(nh * 64 + n * 16 + row16) * 128 + chunk]);
                acc[n] = mfma16(a, bfr, acc[n]);
            }
        }
        const float* pbp = pbAll + j * 128;
#pragma unroll
        for (int n = 0; n < 4; n++) {
            int col = nh * 64 + n * 16 + row16;
            float bi = pbp[col];
#pragma unroll
            for (int r = 0; r < 4; r++) {
                int rel = mh * 16 + g * 4 + r;
                if (rel < width) {
                    int idx = cstart + rel;
                    float val = acc[n][r] + bi + sCur[idx * 128 + col];
                    sCur[idx * 128 + col] = val;
                    if (j == 3) dstb[(size_t)(l0 + rel) * 128 + col] = val;
                }
            }
        }
        __syncthreads();
    }

    // --- stage wq (overlaps final LN; independent LDS ranges) ---
#pragma unroll
    for (int i = 0; i < 4; i++) {
        int e = i * 512 + tid;
        int r = e >> 4, cc = e & 15;
        stage8(&sW[r * 128 + ((cc ^ (r & 15)) << 3)], &wq[(r << 7) + (cc << 3)]);
    }

    // --- final LN of the 32 owned rows -> sLC (swizzled A-tile), 2 rows/pass ---
    int nsum = 0;
#pragma unroll
    for (int i = 0; i < 8; i++) nsum += sred[i];
    float qs = rsqrtf((float)nsum) * 1.44269504089f;  // fold log2(e) for exp2 softmax

#pragma unroll
    for (int rp = 0; rp < 2; rp++) {
        int r = rp * 16 + (w << 1) + sub;  // 0..31
        float4 v = *(const float4*)&sCur[(12 + r) * 128 + (l32 << 2)];
        float mean, rs;
        ln_stats(v, mean, rs);
        u16x4 pk = ln_pack(v, mean, rs);
        int cc = l32 >> 1;
        *(u16x4*)&sLC[r * 128 + ((cc ^ (r & 15)) << 3) + ((l32 & 1) << 2)] = pk;
    }

    // --- QKV projection phases ---
    int mh = w >> 2, nh = w & 3;  // 2 row-halves x 4 col-quarters
#pragma unroll
    for (int y = 0; y < 3; y++) {
        u16* dsty = (y == 0) ? qb : (y == 1) ? kb : vb;
        float sc = (y == 0) ? qs : 1.0f;
        if (y > 0) {
            const float* Wy = (y == 1) ? wk : wv;
            __syncthreads();  // previous-phase sW reads done
#pragma unroll
            for (int i = 0; i < 4; i++) {
                int e = i * 512 + tid;
                int r = e >> 4, cc = e & 15;
                stage8(&sW[r * 128 + ((cc ^ (r & 15)) << 3)], &Wy[(r << 7) + (cc << 3)]);
            }
        }
        __syncthreads();
        f32x4 acc[2] = {zf, zf};
#pragma unroll
        for (int kk = 0; kk < 4; kk++) {
            int chunk = ((kk * 4 + g) ^ row16) << 3;
            bf16x8 a = ldb(&sLC[(mh * 16 + row16) * 128 + chunk]);
#pragma unroll
            for (int n = 0; n < 2; n++) {
                bf16x8 bfr = ldb(&sW[(nh * 32 + n * 16 + row16) * 128 + chunk]);
                acc[n] = mfma16(a, bfr, acc[n]);
            }
        }
#pragma unroll
        for (int n = 0; n < 2; n++) {
            int col = nh * 32 + n * 16 + row16;
#pragma unroll
            for (int r = 0; r < 4; r++) {
                int row = l0 + mh * 16 + g * 4 + r;
                dsty[((size_t)(b << 10) + row) * 128 + col] = f2bf(acc[n][r] * sc);
            }
        }
    }
}

// ---------------- fused wo-GEMM + residual + LN + ff-GEMM + residual (r11 structure) ----------------
__global__ __launch_bounds__(256) void k_wolnff(const u16* __restrict__ X,
                                                const float* __restrict__ wo,
                                                const float* __restrict__ wff,
                                                const float* __restrict__ res,
                                                float* __restrict__ dst) {
    __shared__ alignas(16) u16 sX[64 * 128];
    __shared__ alignas(16) u16 sW1[128 * 128];
    __shared__ alignas(16) u16 sW2[128 * 128];
    int tid = threadIdx.x;
    int w = tid >> 6, l64 = tid & 63;
    int rbase = blockIdx.x * 64;
#pragma unroll
    for (int j = 0; j < 8; j++) {
        int e = j * 256 + tid;
        int r = e >> 4, cc = e & 15;
        int sw = ((cc ^ (r & 15)) << 3);
        stage8(&sW1[r * 128 + sw], &wo[(r << 7) + (cc << 3)]);
        stage8(&sW2[r * 128 + sw], &wff[(r << 7) + (cc << 3)]);
    }
#pragma unroll
    for (int j = 0; j < 4; j++) {
        int e = j * 256 + tid;
        int r = e >> 4, cc = e & 15;
        *(u32x4*)&sX[r * 128 + ((cc ^ (r & 15)) << 3)] =
            *(const u32x4*)&X[((rbase + r) << 7) + (cc << 3)];
    }
    __syncthreads();

    int row16 = l64 & 15, g = l64 >> 4;
    f32x4 zf = {0.f, 0.f, 0.f, 0.f};
    f32x4 acc[8];
#pragma unroll
    for (int n = 0; n < 8; n++) acc[n] = zf;
#pragma unroll
    for (int kk = 0; kk < 4; kk++) {
        int chunk = ((kk * 4 + g) ^ row16) << 3;
        bf16x8 a = ldb(&sX[(w * 16 + row16) * 128 + chunk]);
#pragma unroll
        for (int n = 0; n < 8; n++) {
            bf16x8 bfr = ldb(&sW1[(n * 16 + row16) * 128 + chunk]);
            acc[n] = mfma16(a, bfr, acc[n]);
        }
    }
    f32x4 vals[8];
#pragma unroll
    for (int n = 0; n < 8; n++) {
        int col = n * 16 + row16;
#pragma unroll
        for (int r = 0; r < 4; r++)
            vals[n][r] = acc[n][r] + res[(size_t)(rbase + w * 16 + g * 4 + r) * 128 + col];
    }
    float mean[4], rstd[4];
#pragma unroll
    for (int r = 0; r < 4; r++) {
        float s = 0.f, q = 0.f;
#pragma unroll
        for (int n = 0; n < 8; n++) {
            s += vals[n][r];
            q += vals[n][r] * vals[n][r];
        }
#pragma unroll
        for (int off = 1; off < 16; off <<= 1) {
            s += __shfl_xor(s, off);
            q += __shfl_xor(q, off);
        }
        mean[r] = s * (1.0f / 128.0f);
        float var = q * (1.0f / 128.0f) - mean[r] * mean[r];
        rstd[r] = rsqrtf(var + 1e-5f);
    }
    __syncthreads();
#pragma unroll
    for (int n = 0; n < 8; n++) {
        int col = n * 16 + row16;
        int cc = col >> 3;
#pragma unroll
        for (int r = 0; r < 4; r++) {
            int row = w * 16 + g * 4 + r;
            sX[row * 128 + ((cc ^ (row & 15)) << 3) + (row16 & 7)] =
                f2bf((vals[n][r] - mean[r]) * rstd[r]);
        }
    }
    __syncthreads();
    f32x4 acc2[8];
#pragma unroll
    for (int n = 0; n < 8; n++) acc2[n] = zf;
#pragma unroll
    for (int kk = 0; kk < 4; kk++) {
        int chunk = ((kk * 4 + g) ^ row16) << 3;
        bf16x8 a = ldb(&sX[(w * 16 + row16) * 128 + chunk]);
#pragma unroll
        for (int n = 0; n < 8; n++) {
            bf16x8 bfr = ldb(&sW2[(n * 16 + row16) * 128 + chunk]);
            acc2[n] = mfma16(a, bfr, acc2[n]);
        }
    }
#pragma unroll
    for (int n = 0; n < 8; n++) {
        int col = n * 16 + row16;
#pragma unroll
        for (int r = 0; r < 4; r++)
            dst[(size_t)(rbase + w * 16 + g * 4 + r) * 128 + col] = vals[n][r] + acc2[n][r];
    }
}

// ---------------- fused attention v4 (r19): QT=2 q-tiles/wave, depth-2 K prefetch ----------------
#define LDVF(P)                                                                                \
    ({                                                                                         \
        const u16* vp_ = &sVt[row16 * 1032 + (P) * 32 + (g << 2)];                             \
        union { u16x4 h[2]; u16x8 v8; } uu_;                                                   \
        uu_.h[0] = *(const u16x4*)vp_;                                                         \
        uu_.h[1] = *(const u16x4*)(vp_ + 16);                                                  \
        __builtin_bit_cast(bf16x8, uu_.v8);                                                    \
    })

#define SM_PV(SV, VF, LR, OA)                                                                  \
    {                                                                                          \
        float p0 = ex2(SV[0]), p1 = ex2(SV[1]), p2 = ex2(SV[2]), p3 = ex2(SV[3]);              \
        float p4 = ex2(SV[4]), p5 = ex2(SV[5]), p6 = ex2(SV[6]), p7 = ex2(SV[7]);              \
        LR += ((p0 + p1) + (p2 + p3)) + ((p4 + p5) + (p6 + p7));                               \
        bf16x8 pa = {(__bf16)p0, (__bf16)p1, (__bf16)p2, (__bf16)p3,                           \
                     (__bf16)p4, (__bf16)p5, (__bf16)p6, (__bf16)p7};                          \
        OA = mfma16(VF, pa, OA);                                                               \
    }

__global__ __launch_bounds__(512) void k_attn(const u16* __restrict__ Qg, const u16* __restrict__ Kg,
                                              const u16* __restrict__ Vg,
                                              const int* __restrict__ mask,
                                              u16* __restrict__ Og) {
    __shared__ alignas(16) u16 sVt[16 * 1032];  // 33KB: [d][m], row-padded +8
    __shared__ int sred[8];
    int tid = threadIdx.x;
    int w = tid >> 6, l = tid & 63;
    int bh = blockIdx.x >> 2;
    int qblk = blockIdx.x & 3;
    int b = bh >> 3, h = bh & 7;
    int row16 = l & 15, g = l >> 4;

    const u16* kg = Kg + (size_t)(b << 10) * 128 + (h << 4);
    const u16* vg = Vg + (size_t)(b << 10) * 128 + (h << 4);
#pragma unroll
    for (int j = 0; j < 4; j++) {
        int e = j * 512 + tid;
        int m = e >> 1, half = e & 1;
        u32x4 vv = *(const u32x4*)&vg[m * 128 + half * 8];
        union { u32x4 q; u16 s[8]; } u;
        u.q = vv;
#pragma unroll
        for (int jj = 0; jj < 8; jj++) sVt[(half * 8 + jj) * 1032 + m] = u.s[jj];
    }
    {   // inline per-batch mask sum
        int2 mm = *(const int2*)&mask[(b << 10) + (tid << 1)];
        int part = mm.x + mm.y;
#pragma unroll
        for (int off = 1; off < 64; off <<= 1) part += __shfl_xor(part, off);
        if (l == 0) sred[w] = part;
    }
    __syncthreads();
    int nsum = 0;
#pragma unroll
    for (int i = 0; i < 8; i++) nsum += sred[i];

    int qbase0 = qblk * 256 + w * 32;  // tile t: rows qbase0 + t*16 + row16
    u16x8 z8 = {0, 0, 0, 0, 0, 0, 0, 0};
    const bf16x8 zb = __builtin_bit_cast(bf16x8, z8);
    f32x4 zf = {0.f, 0.f, 0.f, 0.f};

    bool rowv[2];
    bf16x8 qf[2];
    f32x4 oacc[2] = {zf, zf};
    float lrun[2] = {0.0f, 0.0f};
#pragma unroll
    for (int t = 0; t < 2; t++) {
        int q = qbase0 + t * 16 + row16;
        rowv[t] = q < nsum;
        qf[t] = zb;
        if (rowv[t] && g < 2)  // pre-scaled Q; invalid rows: S=0 -> P=1
            qf[t] = ldb(&Qg[(size_t)((b << 10) + q) * 128 + (h << 4) + (g << 3)]);
    }

    const u16* kl = kg + row16 * 128 + (g << 3);  // per-lane K ptr (g<2 lanes), +8KB/pair
    int p = 0;
    if (qbase0 < nsum) {  // wave has at least one valid q-row
        int full = nsum >> 5;
        // depth-2 K prefetch; depth-1 V (LDS)
        bf16x8 ka0 = zb, ka1 = zb, kb0 = zb, kb1 = zb, vc = zb;
        if (full > 0) {
            if (g < 2) {
                ka0 = ldb(kl);
                ka1 = ldb(kl + 2048);
            }
            vc = LDVF(0);
        }
        if (full > 1 && g < 2) {
            kb0 = ldb(kl + 4096);
            kb1 = ldb(kl + 6144);
        }
        for (; p < full; p++) {
            bf16x8 kn0 = zb, kn1 = zb, vn = zb;
            if (p + 2 < full && g < 2) {
                kn0 = ldb(kl + 8192);
                kn1 = ldb(kl + 10240);
            }
            if (p + 1 < full) vn = LDVF(p + 1);
            kl += 4096;
#pragma unroll
            for (int t = 0; t < 2; t++) {
                f32x4 s0 = mfma16(ka0, qf[t], zf);
                f32x4 s1 = mfma16(ka1, qf[t], zf);
                float sv[8];
#pragma unroll
                for (int r = 0; r < 4; r++) {
                    sv[r] = s0[r];
                    sv[4 + r] = s1[r];
                }
                SM_PV(sv, vc, lrun[t], oacc[t])
            }
            ka0 = kb0; ka1 = kb1;
            kb0 = kn0; kb1 = kn1;
            vc = vn;
        }
        if (nsum & 31) {  // one partial pair
            bf16x8 kf0 = zb, kf1 = zb;
            if (g < 2) {
                kf0 = ldb(kl);
                kf1 = ldb(kl + 2048);
            }
            bf16x8 vf = LDVF(p);
            int kb_ = p << 5;
#pragma unroll
            for (int t = 0; t < 2; t++) {
                f32x4 s0 = mfma16(kf0, qf[t], zf);
                f32x4 s1 = mfma16(kf1, qf[t], zf);
                float negfill = rowv[t] ? -1.0e30f : 0.0f;  // invalid rows: P=1 on all cols
                float sv[8];
#pragma unroll
                for (int r = 0; r < 4; r++) {
                    sv[r] = ((kb_ + (g << 2) + r) < nsum) ? s0[r] : negfill;
                    sv[4 + r] = ((kb_ + 16 + (g << 2) + r) < nsum) ? s1[r] : negfill;
                }
                SM_PV(sv, vf, lrun[t], oacc[t])
            }
            p++;
        }
    }
    // tail pairs: only tiles containing invalid rows participate (P=1 on invalid-row lanes)
    bool act0 = (qbase0 + 16 > nsum);
    bool act1 = (qbase0 + 32 > nsum);
    if (act1 && p < 32) {
        int ntail = 32 - p;
        __bf16 c0 = rowv[0] ? (__bf16)0.0f : (__bf16)1.0f;
        __bf16 c1 = rowv[1] ? (__bf16)0.0f : (__bf16)1.0f;
        bf16x8 pt0 = {c0, c0, c0, c0, c0, c0, c0, c0};
        bf16x8 pt1 = {c1, c1, c1, c1, c1, c1, c1, c1};
        if (act0 && !rowv[0]) lrun[0] += 8.0f * (float)ntail;
        if (!rowv[1]) lrun[1] += 8.0f * (float)ntail;
        for (; p < 32; p++) {
            bf16x8 vf = LDVF(p);
            if (act0) oacc[0] = mfma16(vf, pt0, oacc[0]);
            oacc[1] = mfma16(vf, pt1, oacc[1]);
        }
    }

#pragma unroll
    for (int t = 0; t < 2; t++) {
        float lr = lrun[t];
        lr += __shfl_xor(lr, 16);
        lr += __shfl_xor(lr, 32);
        float inv = 1.0f / lr;
        u16x4 ov;
#pragma unroll
        for (int r = 0; r < 4; r++) ov[r] = f2bf(oacc[t][r] * inv);
        int q = qbase0 + t * 16 + row16;
        *(u16x4*)&Og[(size_t)((b << 10) + q) * 128 + (h << 4) + (g << 2)] = ov;
    }
}

extern "C" void kernel_launch(void* const* d_in, const int* in_sizes, int n_in,
                              void* d_out, int out_size, void* d_ws, size_t ws_size,
                              hipStream_t stream) {
    const float* emb     = (const float*)d_in[0];
    const int*   mask    = (const int*)d_in[1];
    const float* depth_w = (const float*)d_in[2];
    const float* depth_b = (const float*)d_in[3];
    const float* pt_w    = (const float*)d_in[4];
    const float* pt_b    = (const float*)d_in[5];
    const float* wq      = (const float*)d_in[6];
    const float* wk      = (const float*)d_in[7];
    const float* wv      = (const float*)d_in[8];
    const float* wo      = (const float*)d_in[9];
    const float* wff     = (const float*)d_in[10];
    float* out = (float*)d_out;
    char* ws = (char*)d_ws;

    u16* qb    = (u16*)(ws + 8388608);
    u16* kb    = (u16*)(ws + 12582912);
    u16* vb    = (u16*)(ws + 16777216);
    u16* attnb = (u16*)(ws + 20971520);

    // conv stack + final LN + QKV projection in one kernel
    k_convstack<<<512, 512, 0, stream>>>(emb, pt_w, depth_w, depth_b, pt_b,
                                         wq, wk, wv, mask, out, qb, kb, vb);
    k_attn<<<512, 512, 0, stream>>>(qb, kb, vb, mask, attnb);
    // wo GEMM + residual + LN + ff GEMM + residual -> out
    k_wolnff<<<256, 256, 0, stream>>>(attnb, wo, wff, out, out);
}

// Round 25
// 76.780 us; speedup vs baseline: 1.0194x; 1.0194x over previous
//
#include <hip/hip_runtime.h>

typedef unsigned short u16;
typedef float f32x4 __attribute__((ext_vector_type(4)));
typedef unsigned int u32x4 __attribute__((ext_vector_type(4)));
typedef unsigned short u16x4 __attribute__((ext_vector_type(4)));
typedef unsigned short u16x8 __attribute__((ext_vector_type(8)));
typedef __bf16 bf16x8 __attribute__((ext_vector_type(8)));

#define DEVFN static __device__ __forceinline__

DEVFN float bf2f(u16 u) {
    unsigned int i = ((unsigned int)u) << 16;
    float f;
    __builtin_memcpy(&f, &i, 4);
    return f;
}
// native RNE bf16 convert — bit-identical to the +0x7fff RNE hack [r18]
DEVFN u16 f2bf(float f) {
    __bf16 h = (__bf16)f;
    return __builtin_bit_cast(u16, h);
}

DEVFN bf16x8 ldb(const u16* p) { return __builtin_bit_cast(bf16x8, *(const u16x8*)p); }

// stage 8 fp32 -> 8 bf16 (RNE, native casts)
DEVFN void stage8(u16* dst, const float* src) {
    float4 a = *(const float4*)src;
    float4 b = *(const float4*)(src + 4);
    u16x8 m;
    m[0] = f2bf(a.x); m[1] = f2bf(a.y); m[2] = f2bf(a.z); m[3] = f2bf(a.w);
    m[4] = f2bf(b.x); m[5] = f2bf(b.y); m[6] = f2bf(b.z); m[7] = f2bf(b.w);
    *(u16x8*)dst = m;
}

// 16x16x32: C/D: col=lane&15 (Brow), row=(lane>>4)*4+reg (Arow)  (HW-verified r2)
DEVFN f32x4 mfma16(bf16x8 a, bf16x8 b, f32x4 c) {
    return __builtin_amdgcn_mfma_f32_16x16x32_bf16(a, b, c, 0, 0, 0);
}

// raw v_exp_f32 (skips denormal fixup). Args are |x|<~4 or -1e30 (raw op -> 0). [r10: WIN]
#if __has_builtin(__builtin_amdgcn_exp2f)
DEVFN float ex2(float x) { return __builtin_amdgcn_exp2f(x); }
#else
DEVFN float ex2(float x) { return exp2f(x); }
#endif

// LN stats for a float4 over a 32-lane row group: 5-level butterfly (offsets <32 keep bit5)
DEVFN void ln_stats(float4 v, float& mean, float& rs) {
    float s = (v.x + v.y) + (v.z + v.w);
    float q = v.x * v.x + v.y * v.y + v.z * v.z + v.w * v.w;
#pragma unroll
    for (int off = 1; off < 32; off <<= 1) {
        s += __shfl_xor(s, off);
        q += __shfl_xor(q, off);
    }
    mean = s * (1.0f / 128.0f);
    float var = q * (1.0f / 128.0f) - mean * mean;
    rs = rsqrtf(var + 1e-5f);
}
DEVFN u16x4 ln_pack(float4 v, float mean, float rs) {
    u16x4 o;
    o[0] = f2bf((v.x - mean) * rs);
    o[1] = f2bf((v.y - mean) * rs);
    o[2] = f2bf((v.z - mean) * rs);
    o[3] = f2bf((v.w - mean) * rs);
    return o;
}

// ---------------- fused 4-layer conv stack + final LN + QKV projection ----------------
// r25: r22 structure + ISOLATED load hoists (dw/db + stage-W into LN region; sW free there
// since previous GEMM's reads end at the loop-end barrier, next read is 3 barriers away)
__global__ __launch_bounds__(512) void k_convstack(const float* __restrict__ x,
                                                   const float* __restrict__ ptw,
                                                   const float* __restrict__ dwAll,
                                                   const float* __restrict__ dbAll,
                                                   const float* __restrict__ pbAll,
                                                   const float* __restrict__ wq,
                                                   const float* __restrict__ wk,
                                                   const float* __restrict__ wv,
                                                   const int* __restrict__ mask,
                                                   float* __restrict__ dst,
                                                   u16* __restrict__ qb,
                                                   u16* __restrict__ kb,
                                                   u16* __restrict__ vb) {
    __shared__ alignas(16) float sCur[56 * 128];  // fp32 residual stream
    __shared__ alignas(16) u16 sLC[64 * 128];     // LN rows / conv tile / final LN A-tile
    __shared__ alignas(16) u16 sW[128 * 128];     // weight tile (bf16, swizzled), restaged
    __shared__ int sred[8];
    int tid = threadIdx.x;
    int w = tid >> 6, l64 = tid & 63;
    int sub = l64 >> 5, l32 = l64 & 31;           // row-half and lane-in-row for LN
    int b = blockIdx.x >> 5, lt = blockIdx.x & 31;
    int l0 = lt << 5;
    const float* xb = x + ((size_t)(b << 10)) * 128;
    float* dstb = dst + ((size_t)(b << 10)) * 128;
    int row16 = l64 & 15, g = l64 >> 4;
    f32x4 zf = {0.f, 0.f, 0.f, 0.f};

    // inline per-batch mask sum (for Q prescale)
    {
        int2 mm = *(const int2*)&mask[(b << 10) + (tid << 1)];
        int part = mm.x + mm.y;
#pragma unroll
        for (int off = 1; off < 64; off <<= 1) part += __shfl_xor(part, off);
        if (l64 == 0) sred[w] = part;
    }

    for (int j = 0; j < 4; j++) {
        int lo = 3 * j;
        int hi = 56 - 3 * j;
        int cstart = lo + 3;
        int width = 50 - 6 * j;

        // --- HOIST 1: stage W_j in the LN region (sW free post loop-end barrier) ---
        const float* Wp = ptw + j * 16384;
#pragma unroll
        for (int i = 0; i < 4; i++) {
            int e = i * 512 + tid;
            int r = e >> 4, cc = e & 15;
            stage8(&sW[r * 128 + ((cc ^ (r & 15)) << 3)], &Wp[(r << 7) + (cc << 3)]);
        }
        // --- HOIST 2: dw/db loads issued before LN (used in conv, 1 barrier later) ---
        int cp = l64;
        const float* dwp = dwAll + j * 896;
        float w0[7], w1[7];
#pragma unroll
        for (int k = 0; k < 7; k++) {
            w0[k] = dwp[(cp * 2) * 7 + k];
            w1[k] = dwp[(cp * 2 + 1) * 7 + k];
        }
        float b0 = dbAll[j * 128 + cp * 2], b1 = dbAll[j * 128 + cp * 2 + 1];

        // --- LN phase: 2 rows per wave-pass ---
        for (int r = lo + (w << 1) + sub; r < hi; r += 16) {
            int al = l0 - 12 + r;
            bool ok = (al >= 0) && (al < 1024);
            float4 v = {0.f, 0.f, 0.f, 0.f};
            if (ok) {
                if (j == 0) v = *(const float4*)&xb[(size_t)al * 128 + (l32 << 2)];
                else        v = *(const float4*)&sCur[r * 128 + (l32 << 2)];
            }
            if (j == 0) *(float4*)&sCur[r * 128 + (l32 << 2)] = v;
            float mean, rs;
            ln_stats(v, mean, rs);
            u16x4 pk = {0, 0, 0, 0};
            if (ok) pk = ln_pack(v, mean, rs);
            *(u16x4*)&sLC[r * 128 + (l32 << 2)] = pk;
        }
        __syncthreads();

        // --- depthwise conv to regs ---
        int base = cstart + w * 7;
        float v0[13], v1[13];
#pragma unroll
        for (int k = 0; k < 13; k++) {
            int rw = base - 3 + k;
            rw = rw < 63 ? rw : 63;
            unsigned int pk = *(const unsigned int*)&sLC[rw * 128 + (cp << 1)];
            v0[k] = bf2f((u16)(pk & 0xffffu));
            v1[k] = bf2f((u16)(pk >> 16));
        }
        float a0[7], a1[7];
#pragma unroll
        for (int rr = 0; rr < 7; rr++) {
            float s0 = b0, s1 = b1;
#pragma unroll
            for (int k = 0; k < 7; k++) {
                s0 += v0[rr + k] * w0[k];
                s1 += v1[rr + k] * w1[k];
            }
            a0[rr] = s0;
            a1[rr] = s1;
        }
        __syncthreads();

#pragma unroll
        for (int rr = 0; rr < 7; rr++) {
            int rel = w * 7 + rr;
            float s0 = (rel < width) ? a0[rr] : 0.0f;
            float s1 = (rel < width) ? a1[rr] : 0.0f;
            int cc = cp >> 2;
            *(unsigned int*)&sLC[rel * 128 + ((cc ^ (rel & 15)) << 3) + ((cp & 3) << 1)] =
                (unsigned int)f2bf(s0) | ((unsigned int)f2bf(s1) << 16);
        }
        *(unsigned int*)&sLC[(56 + w) * 128 + (l64 << 1)] = 0;
        __syncthreads();

        // --- pointwise GEMM ---
        int mh = w >> 1, nh = w & 1;
        f32x4 acc[4] = {zf, zf, zf, zf};
#pragma unroll
        for (int kk = 0; kk < 4; kk++) {
            int chunk = ((kk * 4 + g) ^ row16) << 3;
            bf16x8 a = ldb(&sLC[(mh * 16 + row16) * 128 + chunk]);
#pragma unroll
            for (int n = 0; n < 4; n++) {
                bf16x8 bfr = ldb(&sW[(nh * 64 + n * 16 + row16) * 128 + chunk]);
                acc[n] = mfma16(a, bfr, acc[n]);
            }
        }
        const float* pbp = pbAll + j * 128;
#pragma unroll
        for (int n = 0; n < 4; n++) {
            int col = nh * 64 + n * 16 + row16;
            float bi = pbp[col];
#pragma unroll
            for (int r = 0; r < 4; r++) {
                int rel = mh * 16 + g * 4 + r;
                if (rel < width) {
                    int idx = cstart + rel;
                    float val = acc[n][r] + bi + sCur[idx * 128 + col];
                    sCur[idx * 128 + col] = val;
                    if (j == 3) dstb[(size_t)(l0 + rel) * 128 + col] = val;
                }
            }
        }
        __syncthreads();
    }

    // --- stage wq (overlaps final LN; independent LDS ranges) ---
#pragma unroll
    for (int i = 0; i < 4; i++) {
        int e = i * 512 + tid;
        int r = e >> 4, cc = e & 15;
        stage8(&sW[r * 128 + ((cc ^ (r & 15)) << 3)], &wq[(r << 7) + (cc << 3)]);
    }

    // --- final LN of the 32 owned rows -> sLC (swizzled A-tile), 2 rows/pass ---
    int nsum = 0;
#pragma unroll
    for (int i = 0; i < 8; i++) nsum += sred[i];
    float qs = rsqrtf((float)nsum) * 1.44269504089f;  // fold log2(e) for exp2 softmax

#pragma unroll
    for (int rp = 0; rp < 2; rp++) {
        int r = rp * 16 + (w << 1) + sub;  // 0..31
        float4 v = *(const float4*)&sCur[(12 + r) * 128 + (l32 << 2)];
        float mean, rs;
        ln_stats(v, mean, rs);
        u16x4 pk = ln_pack(v, mean, rs);
        int cc = l32 >> 1;
        *(u16x4*)&sLC[r * 128 + ((cc ^ (r & 15)) << 3) + ((l32 & 1) << 2)] = pk;
    }

    // --- QKV projection phases ---
    int mh = w >> 2, nh = w & 3;  // 2 row-halves x 4 col-quarters
#pragma unroll
    for (int y = 0; y < 3; y++) {
        u16* dsty = (y == 0) ? qb : (y == 1) ? kb : vb;
        float sc = (y == 0) ? qs : 1.0f;
        if (y > 0) {
            const float* Wy = (y == 1) ? wk : wv;
            __syncthreads();  // previous-phase sW reads done
#pragma unroll
            for (int i = 0; i < 4; i++) {
                int e = i * 512 + tid;
                int r = e >> 4, cc = e & 15;
                stage8(&sW[r * 128 + ((cc ^ (r & 15)) << 3)], &Wy[(r << 7) + (cc << 3)]);
            }
        }
        __syncthreads();
        f32x4 acc[2] = {zf, zf};
#pragma unroll
        for (int kk = 0; kk < 4; kk++) {
            int chunk = ((kk * 4 + g) ^ row16) << 3;
            bf16x8 a = ldb(&sLC[(mh * 16 + row16) * 128 + chunk]);
#pragma unroll
            for (int n = 0; n < 2; n++) {
                bf16x8 bfr = ldb(&sW[(nh * 32 + n * 16 + row16) * 128 + chunk]);
                acc[n] = mfma16(a, bfr, acc[n]);
            }
        }
#pragma unroll
        for (int n = 0; n < 2; n++) {
            int col = nh * 32 + n * 16 + row16;
#pragma unroll
            for (int r = 0; r < 4; r++) {
                int row = l0 + mh * 16 + g * 4 + r;
                dsty[((size_t)(b << 10) + row) * 128 + col] = f2bf(acc[n][r] * sc);
            }
        }
    }
}

// ---------------- fused wo-GEMM + residual + LN + ff-GEMM + residual (r11 structure) ----------------
__global__ __launch_bounds__(256) void k_wolnff(const u16* __restrict__ X,
                                                const float* __restrict__ wo,
                                                const float* __restrict__ wff,
                                                const float* __restrict__ res,
                                                float* __restrict__ dst) {
    __shared__ alignas(16) u16 sX[64 * 128];
    __shared__ alignas(16) u16 sW1[128 * 128];
    __shared__ alignas(16) u16 sW2[128 * 128];
    int tid = threadIdx.x;
    int w = tid >> 6, l64 = tid & 63;
    int rbase = blockIdx.x * 64;
#pragma unroll
    for (int j = 0; j < 8; j++) {
        int e = j * 256 + tid;
        int r = e >> 4, cc = e & 15;
        int sw = ((cc ^ (r & 15)) << 3);
        stage8(&sW1[r * 128 + sw], &wo[(r << 7) + (cc << 3)]);
        stage8(&sW2[r * 128 + sw], &wff[(r << 7) + (cc << 3)]);
    }
#pragma unroll
    for (int j = 0; j < 4; j++) {
        int e = j * 256 + tid;
        int r = e >> 4, cc = e & 15;
        *(u32x4*)&sX[r * 128 + ((cc ^ (r & 15)) << 3)] =
            *(const u32x4*)&X[((rbase + r) << 7) + (cc << 3)];
    }
    __syncthreads();

    int row16 = l64 & 15, g = l64 >> 4;
    f32x4 zf = {0.f, 0.f, 0.f, 0.f};
    f32x4 acc[8];
#pragma unroll
    for (int n = 0; n < 8; n++) acc[n] = zf;
#pragma unroll
    for (int kk = 0; kk < 4; kk++) {
        int chunk = ((kk * 4 + g) ^ row16) << 3;
        bf16x8 a = ldb(&sX[(w * 16 + row16) * 128 + chunk]);
#pragma unroll
        for (int n = 0; n < 8; n++) {
            bf16x8 bfr = ldb(&sW1[(n * 16 + row16) * 128 + chunk]);
            acc[n] = mfma16(a, bfr, acc[n]);
        }
    }
    f32x4 vals[8];
#pragma unroll
    for (int n = 0; n < 8; n++) {
        int col = n * 16 + row16;
#pragma unroll
        for (int r = 0; r < 4; r++)
            vals[n][r] = acc[n][r] + res[(size_t)(rbase + w * 16 + g * 4 + r) * 128 + col];
    }
    float mean[4], rstd[4];
#pragma unroll
    for (int r = 0; r < 4; r++) {
        float s = 0.f, q = 0.f;
#pragma unroll
        for (int n = 0; n < 8; n++) {
            s += vals[n][r];
            q += vals[n][r] * vals[n][r];
        }
#pragma unroll
        for (int off = 1; off < 16; off <<= 1) {
            s += __shfl_xor(s, off);
            q += __shfl_xor(q, off);
        }
        mean[r] = s * (1.0f / 128.0f);
        float var = q * (1.0f / 128.0f) - mean[r] * mean[r];
        rstd[r] = rsqrtf(var + 1e-5f);
    }
    __syncthreads();
#pragma unroll
    for (int n = 0; n < 8; n++) {
        int col = n * 16 + row16;
        int cc = col >> 3;
#pragma unroll
        for (int r = 0; r < 4; r++) {
            int row = w * 16 + g * 4 + r;
            sX[row * 128 + ((cc ^ (row & 15)) << 3) + (row16 & 7)] =
                f2bf((vals[n][r] - mean[r]) * rstd[r]);
        }
    }
    __syncthreads();
    f32x4 acc2[8];
#pragma unroll
    for (int n = 0; n < 8; n++) acc2[n] = zf;
#pragma unroll
    for (int kk = 0; kk < 4; kk++) {
        int chunk = ((kk * 4 + g) ^ row16) << 3;
        bf16x8 a = ldb(&sX[(w * 16 + row16) * 128 + chunk]);
#pragma unroll
        for (int n = 0; n < 8; n++) {
            bf16x8 bfr = ldb(&sW2[(n * 16 + row16) * 128 + chunk]);
            acc2[n] = mfma16(a, bfr, acc2[n]);
        }
    }
#pragma unroll
    for (int n = 0; n < 8; n++) {
        int col = n * 16 + row16;
#pragma unroll
        for (int r = 0; r < 4; r++)
            dst[(size_t)(rbase + w * 16 + g * 4 + r) * 128 + col] = vals[n][r] + acc2[n][r];
    }
}

// ---------------- fused attention v4 (r19): QT=2 q-tiles/wave, depth-2 K prefetch ----------------
#define LDVF(P)                                                                                \
    ({                                                                                         \
        const u16* vp_ = &sVt[row16 * 1032 + (P) * 32 + (g << 2)];                             \
        union { u16x4 h[2]; u16x8 v8; } uu_;                                                   \
        uu_.h[0] = *(const u16x4*)vp_;                                                         \
        uu_.h[1] = *(const u16x4*)(vp_ + 16);                                                  \
        __builtin_bit_cast(bf16x8, uu_.v8);                                                    \
    })

#define SM_PV(SV, VF, LR, OA)                                                                  \
    {                                                                                          \
        float p0 = ex2(SV[0]), p1 = ex2(SV[1]), p2 = ex2(SV[2]), p3 = ex2(SV[3]);              \
        float p4 = ex2(SV[4]), p5 = ex2(SV[5]), p6 = ex2(SV[6]), p7 = ex2(SV[7]);              \
        LR += ((p0 + p1) + (p2 + p3)) + ((p4 + p5) + (p6 + p7));                               \
        bf16x8 pa = {(__bf16)p0, (__bf16)p1, (__bf16)p2, (__bf16)p3,                           \
                     (__bf16)p4, (__bf16)p5, (__bf16)p6, (__bf16)p7};                          \
        OA = mfma16(VF, pa, OA);                                                               \
    }

__global__ __launch_bounds__(512) void k_attn(const u16* __restrict__ Qg, const u16* __restrict__ Kg,
                                              const u16* __restrict__ Vg,
                                              const int* __restrict__ mask,
                                              u16* __restrict__ Og) {
    __shared__ alignas(16) u16 sVt[16 * 1032];  // 33KB: [d][m], row-padded +8
    __shared__ int sred[8];
    int tid = threadIdx.x;
    int w = tid >> 6, l = tid & 63;
    int bh = blockIdx.x >> 2;
    int qblk = blockIdx.x & 3;
    int b = bh >> 3, h = bh & 7;
    int row16 = l & 15, g = l >> 4;

    const u16* kg = Kg + (size_t)(b << 10) * 128 + (h << 4);
    const u16* vg = Vg + (size_t)(b << 10) * 128 + (h << 4);
#pragma unroll
    for (int j = 0; j < 4; j++) {
        int e = j * 512 + tid;
        int m = e >> 1, half = e & 1;
        u32x4 vv = *(const u32x4*)&vg[m * 128 + half * 8];
        union { u32x4 q; u16 s[8]; } u;
        u.q = vv;
#pragma unroll
        for (int jj = 0; jj < 8; jj++) sVt[(half * 8 + jj) * 1032 + m] = u.s[jj];
    }
    {   // inline per-batch mask sum
        int2 mm = *(const int2*)&mask[(b << 10) + (tid << 1)];
        int part = mm.x + mm.y;
#pragma unroll
        for (int off = 1; off < 64; off <<= 1) part += __shfl_xor(part, off);
        if (l == 0) sred[w] = part;
    }
    __syncthreads();
    int nsum = 0;
#pragma unroll
    for (int i = 0; i < 8; i++) nsum += sred[i];

    int qbase0 = qblk * 256 + w * 32;  // tile t: rows qbase0 + t*16 + row16
    u16x8 z8 = {0, 0, 0, 0, 0, 0, 0, 0};
    const bf16x8 zb = __builtin_bit_cast(bf16x8, z8);
    f32x4 zf = {0.f, 0.f, 0.f, 0.f};

    bool rowv[2];
    bf16x8 qf[2];
    f32x4 oacc[2] = {zf, zf};
    float lrun[2] = {0.0f, 0.0f};
#pragma unroll
    for (int t = 0; t < 2; t++) {
        int q = qbase0 + t * 16 + row16;
        rowv[t] = q < nsum;
        qf[t] = zb;
        if (rowv[t] && g < 2)  // pre-scaled Q; invalid rows: S=0 -> P=1
            qf[t] = ldb(&Qg[(size_t)((b << 10) + q) * 128 + (h << 4) + (g << 3)]);
    }

    const u16* kl = kg + row16 * 128 + (g << 3);  // per-lane K ptr (g<2 lanes), +8KB/pair
    int p = 0;
    if (qbase0 < nsum) {  // wave has at least one valid q-row
        int full = nsum >> 5;
        // depth-2 K prefetch; depth-1 V (LDS)
        bf16x8 ka0 = zb, ka1 = zb, kb0 = zb, kb1 = zb, vc = zb;
        if (full > 0) {
            if (g < 2) {
                ka0 = ldb(kl);
                ka1 = ldb(kl + 2048);
            }
            vc = LDVF(0);
        }
        if (full > 1 && g < 2) {
            kb0 = ldb(kl + 4096);
            kb1 = ldb(kl + 6144);
        }
        for (; p < full; p++) {
            bf16x8 kn0 = zb, kn1 = zb, vn = zb;
            if (p + 2 < full && g < 2) {
                kn0 = ldb(kl + 8192);
                kn1 = ldb(kl + 10240);
            }
            if (p + 1 < full) vn = LDVF(p + 1);
            kl += 4096;
#pragma unroll
            for (int t = 0; t < 2; t++) {
                f32x4 s0 = mfma16(ka0, qf[t], zf);
                f32x4 s1 = mfma16(ka1, qf[t], zf);
                float sv[8];
#pragma unroll
                for (int r = 0; r < 4; r++) {
                    sv[r] = s0[r];
                    sv[4 + r] = s1[r];
                }
                SM_PV(sv, vc, lrun[t], oacc[t])
            }
            ka0 = kb0; ka1 = kb1;
            kb0 = kn0; kb1 = kn1;
            vc = vn;
        }
        if (nsum & 31) {  // one partial pair
            bf16x8 kf0 = zb, kf1 = zb;
            if (g < 2) {
                kf0 = ldb(kl);
                kf1 = ldb(kl + 2048);
            }
            bf16x8 vf = LDVF(p);
            int kb_ = p << 5;
#pragma unroll
            for (int t = 0; t < 2; t++) {
                f32x4 s0 = mfma16(kf0, qf[t], zf);
                f32x4 s1 = mfma16(kf1, qf[t], zf);
                float negfill = rowv[t] ? -1.0e30f : 0.0f;  // invalid rows: P=1 on all cols
                float sv[8];
#pragma unroll
                for (int r = 0; r < 4; r++) {
                    sv[r] = ((kb_ + (g << 2) + r) < nsum) ? s0[r] : negfill;
                    sv[4 + r] = ((kb_ + 16 + (g << 2) + r) < nsum) ? s1[r] : negfill;
                }
                SM_PV(sv, vf, lrun[t], oacc[t])
            }
            p++;
        }
    }
    // tail pairs: only tiles containing invalid rows participate (P=1 on invalid-row lanes)
    bool act0 = (qbase0 + 16 > nsum);
    bool act1 = (qbase0 + 32 > nsum);
    if (act1 && p < 32) {
        int ntail = 32 - p;
        __bf16 c0 = rowv[0] ? (__bf16)0.0f : (__bf16)1.0f;
        __bf16 c1 = rowv[1] ? (__bf16)0.0f : (__bf16)1.0f;
        bf16x8 pt0 = {c0, c0, c0, c0, c0, c0, c0, c0};
        bf16x8 pt1 = {c1, c1, c1, c1, c1, c1, c1, c1};
        if (act0 && !rowv[0]) lrun[0] += 8.0f * (float)ntail;
        if (!rowv[1]) lrun[1] += 8.0f * (float)ntail;
        for (; p < 32; p++) {
            bf16x8 vf = LDVF(p);
            if (act0) oacc[0] = mfma16(vf, pt0, oacc[0]);
            oacc[1] = mfma16(vf, pt1, oacc[1]);
        }
    }

#pragma unroll
    for (int t = 0; t < 2; t++) {
        float lr = lrun[t];
        lr += __shfl_xor(lr, 16);
        lr += __shfl_xor(lr, 32);
        float inv = 1.0f / lr;
        u16x4 ov;
#pragma unroll
        for (int r = 0; r < 4; r++) ov[r] = f2bf(oacc[t][r] * inv);
        int q = qbase0 + t * 16 + row16;
        *(u16x4*)&Og[(size_t)((b << 10) + q) * 128 + (h << 4) + (g << 2)] = ov;
    }
}

extern "C" void kernel_launch(void* const* d_in, const int* in_sizes, int n_in,
                              void* d_out, int out_size, void* d_ws, size_t ws_size,
                              hipStream_t stream) {
    const float* emb     = (const float*)d_in[0];
    const int*   mask    = (const int*)d_in[1];
    const float* depth_w = (const float*)d_in[2];
    const float* depth_b = (const float*)d_in[3];
    const float* pt_w    = (const float*)d_in[4];
    const float* pt_b    = (const float*)d_in[5];
    const float* wq      = (const float*)d_in[6];
    const float* wk      = (const float*)d_in[7];
    const float* wv      = (const float*)d_in[8];
    const float* wo      = (const float*)d_in[9];
    const float* wff     = (const float*)d_in[10];
    float* out = (float*)d_out;
    char* ws = (char*)d_ws;

    u16* qb    = (u16*)(ws + 8388608);
    u16* kb    = (u16*)(ws + 12582912);
    u16* vb    = (u16*)(ws + 16777216);
    u16* attnb = (u16*)(ws + 20971520);

    // conv stack + final LN + QKV projection in one kernel
    k_convstack<<<512, 512, 0, stream>>>(emb, pt_w, depth_w, depth_b, pt_b,
                                         wq, wk, wv, mask, out, qb, kb, vb);
    k_attn<<<512, 512, 0, stream>>>(qb, kb, vb, mask, attnb);
    // wo GEMM + residual + LN + ff GEMM + residual -> out
    k_wolnff<<<256, 256, 0, stream>>>(attnb, wo, wff, out, out);
}